// Round 13
// baseline (143.112 us; speedup 1.0000x reference)
//
#include <hip/hip_runtime.h>
#include <hip/hip_bf16.h>

#define TV    512
#define TL    64
#define D_    512
#define BKT   64
#define VROWS 64
#define NCHUNK (TV/VROWS)   // 8
#define NKT   (D_/BKT)      // 8

typedef __attribute__((ext_vector_type(8))) short bf16x8;
typedef __attribute__((ext_vector_type(4))) float f32x4;

// async global->LDS DMA, 16B per lane, lane i lands at ldsbase + i*16
__device__ __forceinline__ void gld16(const float* g, void* l) {
  __builtin_amdgcn_global_load_lds(
      (const __attribute__((address_space(1))) unsigned int*)g,
      (__attribute__((address_space(3))) unsigned int*)l, 16, 0, 0);
}

// read one 8-f32 fragment from the XOR-swizzled f32 tile, accumulate norm,
// convert to bf16x8. Swizzle: 16B unit u of row r lives at linear u^(r&7).
__device__ __forceinline__ bf16x8 fragread(const float* tile, int row, int U0,
                                           float* nacc) {
  const char* rp = (const char*)tile + row * 256;
  int s = row & 7;
  f32x4 a0 = *(const f32x4*)(rp + ((U0 ^ s) << 4));
  f32x4 a1 = *(const f32x4*)(rp + (((U0 + 1) ^ s) << 4));
  *nacc += a0[0]*a0[0] + a0[1]*a0[1] + a0[2]*a0[2] + a0[3]*a0[3]
         + a1[0]*a1[0] + a1[1]*a1[1] + a1[2]*a1[2] + a1[3]*a1[3];
  union { bf16x8 v8; __hip_bfloat162 h[4]; } u;
  u.h[0] = __float22bfloat162_rn(make_float2(a0[0], a0[1]));
  u.h[1] = __float22bfloat162_rn(make_float2(a0[2], a0[3]));
  u.h[2] = __float22bfloat162_rn(make_float2(a1[0], a1[1]));
  u.h[3] = __float22bfloat162_rn(make_float2(a1[2], a1[3]));
  return u.v8;
}

__global__ __launch_bounds__(512, 4) void chamfer_main(
    const float* __restrict__ vf, const float* __restrict__ lf,
    const float* __restrict__ mv, const float* __restrict__ ml,
    float* __restrict__ pcol, float* __restrict__ psum)
{
  // XCD-aware decode: all 8 chunks of a batch land on the same XCD.
  const int lin   = blockIdx.x;          // 0..1023
  const int xcd   = lin & 7;
  const int kk    = lin >> 3;            // 0..127
  const int chunk = kk & 7;
  const int b     = ((kk >> 3) << 3) | xcd;   // bijective over 0..127

  const int t     = threadIdx.x;         // 0..511
  const int w     = t >> 6;              // 0..7
  const int lane  = t & 63;
  const int g     = lane >> 4;
  const int c15   = lane & 15;
  const int rt    = w & 3;               // row-tile 0..3 (16 rows)
  const int ch    = w >> 2;              // col-half 0..1 (32 cols)

  // double-buffered f32 tiles, DMA-staged (linear dest, source pre-swizzled)
  __shared__ __align__(16) float lvf[2][VROWS * BKT];  // 2 x 16 KiB
  __shared__ __align__(16) float llf[2][TL * BKT];     // 2 x 16 KiB
  __shared__ float normv_s[VROWS];
  __shared__ float norml_s[TL];
  __shared__ float mvs[VROWS];
  __shared__ float mls[TL];
  __shared__ float rowp[8][16];
  __shared__ float colp[8][32];

  const int v0 = chunk * VROWS;
  const float* vbase = vf + ((size_t)b * TV + v0) * D_;
  const float* lbase = lf + (size_t)b * TL * D_;

  // staging geometry: wave w, call q covers LDS 16B-units idx=(w*2+q)*64+lane
  const int idx0 = (w * 2 + 0) * 64 + lane;
  const int idx1 = (w * 2 + 1) * 64 + lane;
  const int r0 = idx0 >> 4, u0 = idx0 & 15;
  const int r1 = idx1 >> 4, u1 = idx1 & 15;
  // inverse-swizzled global source: linear (row,u) receives global unit u^(row&7)
  const float* gV0 = vbase + (size_t)r0 * D_ + ((u0 ^ (r0 & 7)) << 2);
  const float* gV1 = vbase + (size_t)r1 * D_ + ((u1 ^ (r1 & 7)) << 2);
  const float* gL0 = lbase + (size_t)r0 * D_ + ((u0 ^ (r0 & 7)) << 2);
  const float* gL1 = lbase + (size_t)r1 * D_ + ((u1 ^ (r1 & 7)) << 2);
  const int dst0 = (w * 2 + 0) * 1024;   // wave-uniform LDS byte base
  const int dst1 = (w * 2 + 1) * 1024;

  if (t < VROWS)               mvs[t]       = mv[(size_t)b * TV + v0 + t];
  else if (t < VROWS + TL)     mls[t - 64]  = ml[(size_t)b * TL + (t - 64)];

  f32x4 acc[2];
  acc[0] = (f32x4){0.f, 0.f, 0.f, 0.f};
  acc[1] = (f32x4){0.f, 0.f, 0.f, 0.f};

  float nvacc = 0.f, nl0 = 0.f, nl1 = 0.f;

#define STAGE(BUF, KT) do {                                                      \
    gld16(gV0 + (KT) * BKT, (char*)lvf[BUF] + dst0);                             \
    gld16(gV1 + (KT) * BKT, (char*)lvf[BUF] + dst1);                             \
    gld16(gL0 + (KT) * BKT, (char*)llf[BUF] + dst0);                             \
    gld16(gL1 + (KT) * BKT, (char*)llf[BUF] + dst1);                             \
  } while (0)

#define COMPUTE(BUF) do {                                                        \
    _Pragma("unroll")                                                            \
    for (int ks_ = 0; ks_ < 2; ks_++) {                                          \
      int U0_ = ks_ * 8 + g * 2;                                                 \
      bf16x8 afr_ = fragread(lvf[BUF], rt * 16 + c15, U0_, &nvacc);              \
      bf16x8 bf0_ = fragread(llf[BUF], ch * 32 + c15, U0_, &nl0);                \
      bf16x8 bf1_ = fragread(llf[BUF], ch * 32 + 16 + c15, U0_, &nl1);           \
      acc[0] = __builtin_amdgcn_mfma_f32_16x16x32_bf16(afr_, bf0_, acc[0],0,0,0);\
      acc[1] = __builtin_amdgcn_mfma_f32_16x16x32_bf16(afr_, bf1_, acc[1],0,0,0);\
    }                                                                            \
  } while (0)

  // DMA pipeline: issue tile kt+1 before computing tile kt (zero reg cost)
  STAGE(0, 0);                  __syncthreads();
  STAGE(1, 1);  COMPUTE(0);     __syncthreads();
  STAGE(0, 2);  COMPUTE(1);     __syncthreads();
  STAGE(1, 3);  COMPUTE(0);     __syncthreads();
  STAGE(0, 4);  COMPUTE(1);     __syncthreads();
  STAGE(1, 5);  COMPUTE(0);     __syncthreads();
  STAGE(0, 6);  COMPUTE(1);     __syncthreads();
  STAGE(1, 7);  COMPUTE(0);     __syncthreads();
                COMPUTE(1);
#undef STAGE
#undef COMPUTE

  // ---- norm reductions: sum the 4 g-slices (lanes share c15) ----
  {
    float s = nvacc;  s += __shfl_xor(s, 16);  s += __shfl_xor(s, 32);
    if (ch == 0 && g == 0) normv_s[rt * 16 + c15] = s;
    float s0 = nl0;   s0 += __shfl_xor(s0, 16); s0 += __shfl_xor(s0, 32);
    float s1 = nl1;   s1 += __shfl_xor(s1, 16); s1 += __shfl_xor(s1, 32);
    if (rt == 0 && g == 0) {
      norml_s[ch * 32 + c15]      = s0;
      norml_s[ch * 32 + 16 + c15] = s1;
    }
  }
  __syncthreads();

  // ---- epilogue: pd + masking, row/col mins ----
  const float BIG = 3.0e38f;
  float pdv[2][4];   // [n][j]
  #pragma unroll
  for (int n = 0; n < 2; n++)
    #pragma unroll
    for (int j = 0; j < 4; j++) {
      int row = rt * 16 + g * 4 + j;
      int col = ch * 32 + n * 16 + c15;
      float pd = normv_s[row] + norml_s[col] - 2.0f * acc[n][j];
      bool valid = (mvs[row] != 0.f) && (mls[col] != 0.f);
      pdv[n][j] = valid ? pd : BIG;
    }

  // per-wave row-min over its 32 cols
  #pragma unroll
  for (int j = 0; j < 4; j++) {
    float rm = fminf(pdv[0][j], pdv[1][j]);
    rm = fminf(rm, __shfl_xor(rm, 1));
    rm = fminf(rm, __shfl_xor(rm, 2));
    rm = fminf(rm, __shfl_xor(rm, 4));
    rm = fminf(rm, __shfl_xor(rm, 8));
    if (c15 == 0) rowp[w][g * 4 + j] = rm;
  }
  // per-wave col-min over its 16 rows
  #pragma unroll
  for (int n = 0; n < 2; n++) {
    float cm = fminf(fminf(pdv[n][0], pdv[n][1]),
                     fminf(pdv[n][2], pdv[n][3]));
    cm = fminf(cm, __shfl_xor(cm, 16));
    cm = fminf(cm, __shfl_xor(cm, 32));
    if (g == 0) colp[w][n * 16 + c15] = cm;
  }
  __syncthreads();

  if (t < 64) {
    // rows: combine the two col-halves (waves rt and rt+4), masked sum
    int row = t;
    float rm = fminf(rowp[row >> 4][row & 15], rowp[(row >> 4) + 4][row & 15]);
    float sl = (mvs[row] != 0.f) ? rm : 0.f;
    #pragma unroll
    for (int s = 1; s < 64; s <<= 1) sl += __shfl_xor(sl, s);
    if (t == 0) psum[(size_t)b * NCHUNK + chunk] = sl;
    // cols: combine the 4 row-tiles of this col-half
    int col = t;
    int chh = col >> 5, lc = col & 31;
    float cm = fminf(fminf(colp[chh * 4 + 0][lc], colp[chh * 4 + 1][lc]),
                     fminf(colp[chh * 4 + 2][lc], colp[chh * 4 + 3][lc]));
    pcol[((size_t)b * NCHUNK + chunk) * TL + col] = cm;
  }
}

__global__ __launch_bounds__(64) void chamfer_fin(
    const float* __restrict__ pcol, const float* __restrict__ psum,
    const float* __restrict__ mv, const float* __restrict__ ml,
    float* __restrict__ out)
{
  int b = blockIdx.x;
  int l = threadIdx.x;
  float cm = pcol[((size_t)b * NCHUNK + 0) * 64 + l];
  #pragma unroll
  for (int i = 1; i < NCHUNK; i++)
    cm = fminf(cm, pcol[((size_t)b * NCHUNK + i) * 64 + l]);
  float mlv = ml[(size_t)b * 64 + l];
  float sl = (mlv != 0.f) ? cm : 0.f;
  float nl = mlv;
  float nv = 0.f;
  #pragma unroll
  for (int i = 0; i < 8; i++) nv += mv[(size_t)b * 512 + l * 8 + i];
  float sv = (l < NCHUNK) ? psum[(size_t)b * NCHUNK + l] : 0.f;
  #pragma unroll
  for (int s = 1; s < 64; s <<= 1) {
    sl += __shfl_xor(sl, s);
    nl += __shfl_xor(nl, s);
    nv += __shfl_xor(nv, s);
    sv += __shfl_xor(sv, s);
  }
  if (l == 0) out[b] = sl / nl + sv / nv;
}

extern "C" void kernel_launch(void* const* d_in, const int* in_sizes, int n_in,
                              void* d_out, int out_size, void* d_ws, size_t ws_size,
                              hipStream_t stream) {
  const float* vf = (const float*)d_in[0];
  const float* lf = (const float*)d_in[1];
  const float* mv = (const float*)d_in[2];
  const float* ml = (const float*)d_in[3];
  float* out  = (float*)d_out;
  float* pcol = (float*)d_ws;                       // [128][8][64]
  float* psum = pcol + 128 * NCHUNK * 64;           // [128][8]
  chamfer_main<<<128 * NCHUNK, 512, 0, stream>>>(vf, lf, mv, ml, pcol, psum);
  chamfer_fin<<<128, 64, 0, stream>>>(pcol, psum, mv, ml, out);
}

// Round 14
// 36.120 us; speedup vs baseline: 3.9621x; 3.9621x over previous
//
#include <hip/hip_runtime.h>
#include <hip/hip_bf16.h>

#define TV    512
#define TL    64
#define D_    512
#define BKT   64
#define VROWS 32
#define NCHUNK (TV/VROWS)   // 16
#define NKT   (D_/BKT)      // 8

typedef __attribute__((ext_vector_type(8))) short bf16x8;
typedef __attribute__((ext_vector_type(4))) float f32x4;

__global__ __launch_bounds__(256, 8) void chamfer_main(
    const float* __restrict__ vf, const float* __restrict__ lf,
    const float* __restrict__ mv, const float* __restrict__ ml,
    float* __restrict__ pcol, float* __restrict__ psum)
{
  // XCD-aware decode: all 16 chunks of a batch land on the same XCD.
  const int lin   = blockIdx.x;          // 0..2047
  const int xcd   = lin & 7;
  const int kk    = lin >> 3;            // 0..255
  const int chunk = kk & 15;
  const int b     = ((kk >> 4) << 3) | xcd;   // bijective over 0..127

  const int t     = threadIdx.x;         // 0..255
  const int w     = t >> 6;              // 0..3
  const int lane  = t & 63;
  const int g     = lane >> 4;
  const int c15   = lane & 15;
  const int rt    = w & 1;               // row-tile 0..1 (16 rows)
  const int ch    = w >> 1;              // col-half 0..1 (32 cols)
  const int srow  = t >> 3;              // staging row 0..31
  const int skc   = t & 7;               // staging k-chunk (8 floats)

  // single-buffered swizzled bf16 tiles; proven transient staging idiom
  __shared__ __align__(16) short lv[VROWS * BKT];  // 4 KiB
  __shared__ __align__(16) short ll[TL * BKT];     // 8 KiB
  __shared__ float normv_s[VROWS];
  __shared__ float norml_s[TL];
  __shared__ float mvs[VROWS];
  __shared__ float mls[TL];
  __shared__ float rowp[4][16];
  __shared__ float colp[4][32];

  const int v0 = chunk * VROWS;
  const float* vbase = vf + ((size_t)b * TV + v0) * D_;
  const float* lbase = lf + (size_t)b * TL * D_;
  const float* vsrc = vbase + (size_t)srow * D_ + skc * 8;
  const float* lsrc0 = lbase + (size_t)srow * D_ + skc * 8;
  const float* lsrc1 = lbase + (size_t)(32 + srow) * D_ + skc * 8;

  if (t < VROWS)                mvs[t]        = mv[(size_t)b * TV + v0 + t];
  else if (t < VROWS + TL)      mls[t - VROWS] = ml[(size_t)b * TL + (t - VROWS)];

  f32x4 acc[2];
  acc[0] = (f32x4){0.f, 0.f, 0.f, 0.f};
  acc[1] = (f32x4){0.f, 0.f, 0.f, 0.f};

  float nvacc = 0.f;            // V row srow partial
  float nlacc[2] = {0.f, 0.f};  // L rows srow, srow+32

  const int soff  = (srow * 128 + skc * 16) ^ ((srow & 7) << 4);
  const int soff1 = ((32 + srow) * 128 + skc * 16) ^ ((srow & 7) << 4);

  for (int kt = 0; kt < NKT; ++kt) {
    // ---- stage V 32x64 + L 64x64 (bf16, swizzled), fully transient ----
    {
      const float4* sv_ = (const float4*)(vsrc + kt * BKT);
      float4 a = sv_[0], bq = sv_[1];
      nvacc += a.x*a.x + a.y*a.y + a.z*a.z + a.w*a.w
             + bq.x*bq.x + bq.y*bq.y + bq.z*bq.z + bq.w*bq.w;
      union { bf16x8 v8; __hip_bfloat162 h[4]; } u;
      u.h[0] = __float22bfloat162_rn(make_float2(a.x, a.y));
      u.h[1] = __float22bfloat162_rn(make_float2(a.z, a.w));
      u.h[2] = __float22bfloat162_rn(make_float2(bq.x, bq.y));
      u.h[3] = __float22bfloat162_rn(make_float2(bq.z, bq.w));
      *(bf16x8*)((char*)lv + soff) = u.v8;
    }
    {
      const float4* sl_ = (const float4*)(lsrc0 + kt * BKT);
      float4 c = sl_[0], dq = sl_[1];
      nlacc[0] += c.x*c.x + c.y*c.y + c.z*c.z + c.w*c.w
                + dq.x*dq.x + dq.y*dq.y + dq.z*dq.z + dq.w*dq.w;
      union { bf16x8 v8; __hip_bfloat162 h[4]; } u2;
      u2.h[0] = __float22bfloat162_rn(make_float2(c.x, c.y));
      u2.h[1] = __float22bfloat162_rn(make_float2(c.z, c.w));
      u2.h[2] = __float22bfloat162_rn(make_float2(dq.x, dq.y));
      u2.h[3] = __float22bfloat162_rn(make_float2(dq.z, dq.w));
      *(bf16x8*)((char*)ll + soff) = u2.v8;
    }
    {
      const float4* sl_ = (const float4*)(lsrc1 + kt * BKT);
      float4 c = sl_[0], dq = sl_[1];
      nlacc[1] += c.x*c.x + c.y*c.y + c.z*c.z + c.w*c.w
                + dq.x*dq.x + dq.y*dq.y + dq.z*dq.z + dq.w*dq.w;
      union { bf16x8 v8; __hip_bfloat162 h[4]; } u2;
      u2.h[0] = __float22bfloat162_rn(make_float2(c.x, c.y));
      u2.h[1] = __float22bfloat162_rn(make_float2(c.z, c.w));
      u2.h[2] = __float22bfloat162_rn(make_float2(dq.x, dq.y));
      u2.h[3] = __float22bfloat162_rn(make_float2(dq.z, dq.w));
      *(bf16x8*)((char*)ll + soff1) = u2.v8;
    }
    __syncthreads();
    // ---- MFMA: wave (rt, ch); 2 k-steps of 32 ----
    #pragma unroll
    for (int ks = 0; ks < 2; ks++) {
      bf16x8 afr, bfr[2];
      {
        int row = rt * 16 + c15;
        int off = (row * 128 + ks * 64 + g * 16) ^ ((row & 7) << 4);
        afr = *(const bf16x8*)((const char*)lv + off);
      }
      #pragma unroll
      for (int n = 0; n < 2; n++) {
        int row = ch * 32 + n * 16 + c15;
        int off = (row * 128 + ks * 64 + g * 16) ^ ((row & 7) << 4);
        bfr[n] = *(const bf16x8*)((const char*)ll + off);
      }
      #pragma unroll
      for (int n = 0; n < 2; n++)
        acc[n] = __builtin_amdgcn_mfma_f32_16x16x32_bf16(afr, bfr[n], acc[n], 0, 0, 0);
    }
    __syncthreads();
  }

  // ---- row-norm reductions (8 consecutive lanes share a staged row) ----
  {
    float s = nvacc;
    s += __shfl_xor(s, 1); s += __shfl_xor(s, 2); s += __shfl_xor(s, 4);
    if ((t & 7) == 0) normv_s[srow] = s;
    float s0 = nlacc[0];
    s0 += __shfl_xor(s0, 1); s0 += __shfl_xor(s0, 2); s0 += __shfl_xor(s0, 4);
    if ((t & 7) == 0) norml_s[srow] = s0;
    float s1 = nlacc[1];
    s1 += __shfl_xor(s1, 1); s1 += __shfl_xor(s1, 2); s1 += __shfl_xor(s1, 4);
    if ((t & 7) == 0) norml_s[32 + srow] = s1;
  }
  __syncthreads();

  // ---- epilogue: pd + masking, row/col mins ----
  const float BIG = 3.0e38f;
  float pdv[2][4];   // [n][j]
  #pragma unroll
  for (int n = 0; n < 2; n++)
    #pragma unroll
    for (int j = 0; j < 4; j++) {
      int row = rt * 16 + g * 4 + j;
      int col = ch * 32 + n * 16 + c15;
      float pd = normv_s[row] + norml_s[col] - 2.0f * acc[n][j];
      bool valid = (mvs[row] != 0.f) && (mls[col] != 0.f);
      pdv[n][j] = valid ? pd : BIG;
    }

  // per-wave row-min over its 32 cols
  #pragma unroll
  for (int j = 0; j < 4; j++) {
    float rm = fminf(pdv[0][j], pdv[1][j]);
    rm = fminf(rm, __shfl_xor(rm, 1));
    rm = fminf(rm, __shfl_xor(rm, 2));
    rm = fminf(rm, __shfl_xor(rm, 4));
    rm = fminf(rm, __shfl_xor(rm, 8));
    if (c15 == 0) rowp[w][g * 4 + j] = rm;
  }
  // per-wave col-min over its 16 rows
  #pragma unroll
  for (int n = 0; n < 2; n++) {
    float cm = fminf(fminf(pdv[n][0], pdv[n][1]),
                     fminf(pdv[n][2], pdv[n][3]));
    cm = fminf(cm, __shfl_xor(cm, 16));
    cm = fminf(cm, __shfl_xor(cm, 32));
    if (g == 0) colp[w][n * 16 + c15] = cm;
  }
  __syncthreads();

  if (t < VROWS) {
    // rows: combine the two col-halves (waves rt and rt+2), masked sum
    int row = t;
    float rm = fminf(rowp[(row >> 4)][row & 15], rowp[(row >> 4) + 2][row & 15]);
    float sl = (mvs[row] != 0.f) ? rm : 0.f;
    #pragma unroll
    for (int s = 1; s < 32; s <<= 1) sl += __shfl_xor(sl, s);
    if (t == 0) psum[(size_t)b * NCHUNK + chunk] = sl;
  }
  if (t < TL) {
    // cols: combine the 2 row-tiles of this col-half
    int col = t;
    int chh = col >> 5, lc = col & 31;
    float cm = fminf(colp[chh * 2 + 0][lc], colp[chh * 2 + 1][lc]);
    pcol[((size_t)b * NCHUNK + chunk) * TL + col] = cm;
  }
}

__global__ __launch_bounds__(64) void chamfer_fin(
    const float* __restrict__ pcol, const float* __restrict__ psum,
    const float* __restrict__ mv, const float* __restrict__ ml,
    float* __restrict__ out)
{
  int b = blockIdx.x;
  int l = threadIdx.x;
  float cm = pcol[((size_t)b * NCHUNK + 0) * 64 + l];
  #pragma unroll
  for (int i = 1; i < NCHUNK; i++)
    cm = fminf(cm, pcol[((size_t)b * NCHUNK + i) * 64 + l]);
  float mlv = ml[(size_t)b * 64 + l];
  float sl = (mlv != 0.f) ? cm : 0.f;
  float nl = mlv;
  float nv = 0.f;
  #pragma unroll
  for (int i = 0; i < 8; i++) nv += mv[(size_t)b * 512 + l * 8 + i];
  float sv = (l < NCHUNK) ? psum[(size_t)b * NCHUNK + l] : 0.f;
  #pragma unroll
  for (int s = 1; s < 64; s <<= 1) {
    sl += __shfl_xor(sl, s);
    nl += __shfl_xor(nl, s);
    nv += __shfl_xor(nv, s);
    sv += __shfl_xor(sv, s);
  }
  if (l == 0) out[b] = sl / nl + sv / nv;
}

extern "C" void kernel_launch(void* const* d_in, const int* in_sizes, int n_in,
                              void* d_out, int out_size, void* d_ws, size_t ws_size,
                              hipStream_t stream) {
  const float* vf = (const float*)d_in[0];
  const float* lf = (const float*)d_in[1];
  const float* mv = (const float*)d_in[2];
  const float* ml = (const float*)d_in[3];
  float* out  = (float*)d_out;
  float* pcol = (float*)d_ws;                       // [128][16][64]
  float* psum = pcol + 128 * NCHUNK * 64;           // [128][16]
  chamfer_main<<<128 * NCHUNK, 256, 0, stream>>>(vf, lf, mv, ml, pcol, psum);
  chamfer_fin<<<128, 64, 0, stream>>>(pcol, psum, mv, ml, out);
}

// Round 15
// 34.155 us; speedup vs baseline: 4.1901x; 1.0575x over previous
//
#include <hip/hip_runtime.h>
#include <hip/hip_bf16.h>

#define TV    512
#define TL    64
#define D_    512
#define BKT   64
#define VROWS 64
#define NCHUNK (TV/VROWS)   // 8
#define NKT   (D_/BKT)      // 8

typedef __attribute__((ext_vector_type(8))) short bf16x8;
typedef __attribute__((ext_vector_type(4))) float f32x4;

__global__ __launch_bounds__(512, 4) void chamfer_main(
    const float* __restrict__ vf, const float* __restrict__ lf,
    const float* __restrict__ mv, const float* __restrict__ ml,
    float* __restrict__ pcol, float* __restrict__ psum)
{
  // XCD-aware decode: all 8 chunks of a batch land on the same XCD.
  const int lin   = blockIdx.x;          // 0..1023
  const int xcd   = lin & 7;
  const int kk    = lin >> 3;            // 0..127
  const int chunk = kk & 7;
  const int b     = ((kk >> 3) << 3) | xcd;   // bijective over 0..127

  const int t     = threadIdx.x;         // 0..511
  const int w     = t >> 6;              // 0..7
  const int lane  = t & 63;
  const int g     = lane >> 4;
  const int c15   = lane & 15;
  const int rt    = w & 3;               // row-tile 0..3 (16 rows)
  const int ch    = w >> 2;              // col-half 0..1 (32 cols)
  const int srow  = t >> 3;              // staging row 0..63
  const int skc   = t & 7;               // staging k-chunk (8 floats)

  // double-buffered swizzled bf16 tiles; ONE barrier per K-tile.
  // Payload registers live only WITHIN an interval (never across a barrier).
  __shared__ __align__(16) short lv[2][VROWS * BKT];  // 2 x 8 KiB
  __shared__ __align__(16) short ll[2][TL * BKT];     // 2 x 8 KiB
  __shared__ float normv_s[VROWS];
  __shared__ float norml_s[TL];
  __shared__ float mvs[VROWS];
  __shared__ float mls[TL];
  __shared__ float rowp[8][16];
  __shared__ float colp[8][32];

  const int v0 = chunk * VROWS;
  const float* vbase = vf + ((size_t)b * TV + v0) * D_;
  const float* lbase = lf + (size_t)b * TL * D_;
  const float4* vsrc4 = (const float4*)(vbase + (size_t)srow * D_ + skc * 8);
  const float4* lsrc4 = (const float4*)(lbase + (size_t)srow * D_ + skc * 8);

  if (t < VROWS)                mvs[t]        = mv[(size_t)b * TV + v0 + t];
  else if (t < VROWS + TL)      mls[t - VROWS] = ml[(size_t)b * TL + (t - VROWS)];

  f32x4 acc[2];
  acc[0] = (f32x4){0.f, 0.f, 0.f, 0.f};
  acc[1] = (f32x4){0.f, 0.f, 0.f, 0.f};

  float nvacc = 0.f;   // V row srow partial (8 lanes share a row)
  float nlacc = 0.f;   // L row srow partial

  const int soff = (srow * 128 + skc * 16) ^ ((srow & 7) << 4);

#define CVTST(BUF, VA0, VA1, LA0, LA1) do {                                      \
    nvacc += VA0.x*VA0.x + VA0.y*VA0.y + VA0.z*VA0.z + VA0.w*VA0.w               \
           + VA1.x*VA1.x + VA1.y*VA1.y + VA1.z*VA1.z + VA1.w*VA1.w;              \
    union { bf16x8 v8; __hip_bfloat162 h[4]; } u_;                               \
    u_.h[0] = __float22bfloat162_rn(make_float2(VA0.x, VA0.y));                  \
    u_.h[1] = __float22bfloat162_rn(make_float2(VA0.z, VA0.w));                  \
    u_.h[2] = __float22bfloat162_rn(make_float2(VA1.x, VA1.y));                  \
    u_.h[3] = __float22bfloat162_rn(make_float2(VA1.z, VA1.w));                  \
    *(bf16x8*)((char*)lv[BUF] + soff) = u_.v8;                                   \
    nlacc += LA0.x*LA0.x + LA0.y*LA0.y + LA0.z*LA0.z + LA0.w*LA0.w               \
           + LA1.x*LA1.x + LA1.y*LA1.y + LA1.z*LA1.z + LA1.w*LA1.w;              \
    union { bf16x8 v8; __hip_bfloat162 h[4]; } u2_;                              \
    u2_.h[0] = __float22bfloat162_rn(make_float2(LA0.x, LA0.y));                 \
    u2_.h[1] = __float22bfloat162_rn(make_float2(LA0.z, LA0.w));                 \
    u2_.h[2] = __float22bfloat162_rn(make_float2(LA1.x, LA1.y));                 \
    u2_.h[3] = __float22bfloat162_rn(make_float2(LA1.z, LA1.w));                 \
    *(bf16x8*)((char*)ll[BUF] + soff) = u2_.v8;                                  \
  } while (0)

#define MFMA_TILE(BUF) do {                                                      \
    _Pragma("unroll")                                                            \
    for (int ks_ = 0; ks_ < 2; ks_++) {                                          \
      bf16x8 afr_, bfr_[2];                                                      \
      {                                                                          \
        int row_ = rt * 16 + c15;                                                \
        int off_ = (row_ * 128 + ks_ * 64 + g * 16) ^ ((row_ & 7) << 4);         \
        afr_ = *(const bf16x8*)((const char*)lv[BUF] + off_);                    \
      }                                                                          \
      _Pragma("unroll")                                                          \
      for (int n_ = 0; n_ < 2; n_++) {                                           \
        int row_ = ch * 32 + n_ * 16 + c15;                                      \
        int off_ = (row_ * 128 + ks_ * 64 + g * 16) ^ ((row_ & 7) << 4);         \
        bfr_[n_] = *(const bf16x8*)((const char*)ll[BUF] + off_);                \
      }                                                                          \
      _Pragma("unroll")                                                          \
      for (int n_ = 0; n_ < 2; n_++)                                             \
        acc[n_] = __builtin_amdgcn_mfma_f32_16x16x32_bf16(                       \
            afr_, bfr_[n_], acc[n_], 0, 0, 0);                                   \
    }                                                                            \
  } while (0)

  // interval kt: issue loads(kt+1) -> MFMA(kt) from buf[kt&1] ->
  //              cvt+store(kt+1) into buf[(kt+1)&1] -> barrier
#define STEP(KT) do {                                                            \
    float4 va0 = vsrc4[((KT) + 1) * 16],  va1 = vsrc4[((KT) + 1) * 16 + 1];      \
    float4 la0 = lsrc4[((KT) + 1) * 16],  la1 = lsrc4[((KT) + 1) * 16 + 1];      \
    MFMA_TILE((KT) & 1);                                                         \
    CVTST(((KT) + 1) & 1, va0, va1, la0, la1);                                   \
    __syncthreads();                                                             \
  } while (0)

  // prologue: stage tile 0 into buf0
  {
    float4 va0 = vsrc4[0], va1 = vsrc4[1];
    float4 la0 = lsrc4[0], la1 = lsrc4[1];
    CVTST(0, va0, va1, la0, la1);
    __syncthreads();
  }
  STEP(0); STEP(1); STEP(2); STEP(3); STEP(4); STEP(5); STEP(6);
  MFMA_TILE(7 & 1);
#undef STEP
#undef CVTST
#undef MFMA_TILE

  // ---- row-norm reductions (8 consecutive lanes share a staged row) ----
  {
    float s = nvacc;
    s += __shfl_xor(s, 1); s += __shfl_xor(s, 2); s += __shfl_xor(s, 4);
    if ((t & 7) == 0) normv_s[srow] = s;
    float s2 = nlacc;
    s2 += __shfl_xor(s2, 1); s2 += __shfl_xor(s2, 2); s2 += __shfl_xor(s2, 4);
    if ((t & 7) == 0) norml_s[srow] = s2;
  }
  __syncthreads();

  // ---- epilogue: pd + masking, row/col mins ----
  const float BIG = 3.0e38f;
  float pdv[2][4];   // [n][j]
  #pragma unroll
  for (int n = 0; n < 2; n++)
    #pragma unroll
    for (int j = 0; j < 4; j++) {
      int row = rt * 16 + g * 4 + j;
      int col = ch * 32 + n * 16 + c15;
      float pd = normv_s[row] + norml_s[col] - 2.0f * acc[n][j];
      bool valid = (mvs[row] != 0.f) && (mls[col] != 0.f);
      pdv[n][j] = valid ? pd : BIG;
    }

  // per-wave row-min over its 32 cols
  #pragma unroll
  for (int j = 0; j < 4; j++) {
    float rm = fminf(pdv[0][j], pdv[1][j]);
    rm = fminf(rm, __shfl_xor(rm, 1));
    rm = fminf(rm, __shfl_xor(rm, 2));
    rm = fminf(rm, __shfl_xor(rm, 4));
    rm = fminf(rm, __shfl_xor(rm, 8));
    if (c15 == 0) rowp[w][g * 4 + j] = rm;
  }
  // per-wave col-min over its 16 rows
  #pragma unroll
  for (int n = 0; n < 2; n++) {
    float cm = fminf(fminf(pdv[n][0], pdv[n][1]),
                     fminf(pdv[n][2], pdv[n][3]));
    cm = fminf(cm, __shfl_xor(cm, 16));
    cm = fminf(cm, __shfl_xor(cm, 32));
    if (g == 0) colp[w][n * 16 + c15] = cm;
  }
  __syncthreads();

  if (t < 64) {
    // rows: combine the two col-halves (waves rt and rt+4), masked sum
    int row = t;
    float rm = fminf(rowp[row >> 4][row & 15], rowp[(row >> 4) + 4][row & 15]);
    float sl = (mvs[row] != 0.f) ? rm : 0.f;
    #pragma unroll
    for (int s = 1; s < 64; s <<= 1) sl += __shfl_xor(sl, s);
    if (t == 0) psum[(size_t)b * NCHUNK + chunk] = sl;
    // cols: combine the 4 row-tiles of this col-half
    int col = t;
    int chh = col >> 5, lc = col & 31;
    float cm = fminf(fminf(colp[chh * 4 + 0][lc], colp[chh * 4 + 1][lc]),
                     fminf(colp[chh * 4 + 2][lc], colp[chh * 4 + 3][lc]));
    pcol[((size_t)b * NCHUNK + chunk) * TL + col] = cm;
  }
}

__global__ __launch_bounds__(64) void chamfer_fin(
    const float* __restrict__ pcol, const float* __restrict__ psum,
    const float* __restrict__ mv, const float* __restrict__ ml,
    float* __restrict__ out)
{
  int b = blockIdx.x;
  int l = threadIdx.x;
  float cm = pcol[((size_t)b * NCHUNK + 0) * 64 + l];
  #pragma unroll
  for (int i = 1; i < NCHUNK; i++)
    cm = fminf(cm, pcol[((size_t)b * NCHUNK + i) * 64 + l]);
  float mlv = ml[(size_t)b * 64 + l];
  float sl = (mlv != 0.f) ? cm : 0.f;
  float nl = mlv;
  float nv = 0.f;
  #pragma unroll
  for (int i = 0; i < 8; i++) nv += mv[(size_t)b * 512 + l * 8 + i];
  float sv = (l < NCHUNK) ? psum[(size_t)b * NCHUNK + l] : 0.f;
  #pragma unroll
  for (int s = 1; s < 64; s <<= 1) {
    sl += __shfl_xor(sl, s);
    nl += __shfl_xor(nl, s);
    nv += __shfl_xor(nv, s);
    sv += __shfl_xor(sv, s);
  }
  if (l == 0) out[b] = sl / nl + sv / nv;
}

extern "C" void kernel_launch(void* const* d_in, const int* in_sizes, int n_in,
                              void* d_out, int out_size, void* d_ws, size_t ws_size,
                              hipStream_t stream) {
  const float* vf = (const float*)d_in[0];
  const float* lf = (const float*)d_in[1];
  const float* mv = (const float*)d_in[2];
  const float* ml = (const float*)d_in[3];
  float* out  = (float*)d_out;
  float* pcol = (float*)d_ws;                       // [128][8][64]
  float* psum = pcol + 128 * NCHUNK * 64;           // [128][8]
  chamfer_main<<<128 * NCHUNK, 512, 0, stream>>>(vf, lf, mv, ml, pcol, psum);
  chamfer_fin<<<128, 64, 0, stream>>>(pcol, psum, mv, ml, out);
}